// Round 6
// baseline (1448.510 us; speedup 1.0000x reference)
//
#include <hip/hip_runtime.h>
#include <hip/hip_bf16.h>
#include <stdint.h>

typedef unsigned int u32;
typedef unsigned char u8;
typedef unsigned long long u64;
typedef __attribute__((ext_vector_type(8))) int i32x8;
typedef __attribute__((ext_vector_type(4))) int i32x4;
typedef __attribute__((ext_vector_type(4))) float f32x4;

#define NROWS 8192    // 16*512
#define NCODES 4096
#define DIM 4096
#define BK 128
#define KSTEPS (DIM / BK)   // 32
#define BM 256
#define BN 256

// ---------------- workspace layout (bytes) ----------------
#define OFF_A      0UL
#define OFF_B      33554432UL
#define OFF_NORMS  50331648UL
#define OFF_RN     50348032UL
#define OFF_AMIN   50380800UL
#define OFF_COUNTS 50446336UL

__device__ __forceinline__ void stage16(const void* g, void* l) {
  __builtin_amdgcn_global_load_lds(
      (const __attribute__((address_space(1))) u32*)g,
      (__attribute__((address_space(3))) u32*)l, 16, 0, 0);
}

// float -> OCP e4m3fn, RNE, saturate to 448. Data is finite (no NaN path).
__device__ __forceinline__ u32 f2fp8(float f) {
  u32 u = __float_as_uint(f);
  u32 sign = (u >> 24) & 0x80u;
  u32 mag = u & 0x7FFFFFFFu;
  if (mag > 0x43E00000u) mag = 0x43E00000u;          // sat to 448
  u32 b;
  if (mag < 0x3C800000u) {                            // < 2^-6 : subnormal
    b = (u32)__float2int_rn(__uint_as_float(mag) * 512.0f);
  } else {
    u32 m = mag + 0x7FFFFu + ((mag >> 20) & 1u);      // RNE at 20-bit boundary
    u32 e = (m >> 23) - 127u;
    b = (((e + 7u) << 3) | ((m >> 20) & 7u)) & 0x7Fu;
  }
  return sign | b;
}

__device__ __forceinline__ u32 pack4(float4 v) {
  return f2fp8(v.x) | (f2fp8(v.y) << 8) | (f2fp8(v.z) << 16) | (f2fp8(v.w) << 24);
}

__device__ __forceinline__ float waveRed(float s) {
#pragma unroll
  for (int off = 32; off > 0; off >>= 1) s += __shfl_down(s, off);
  return s;
}

__device__ __forceinline__ i32x8 comb(i32x4 lo, i32x4 hi) {
  i32x8 r;
  r[0] = lo[0]; r[1] = lo[1]; r[2] = lo[2]; r[3] = lo[3];
  r[4] = hi[0]; r[5] = hi[1]; r[6] = hi[2]; r[7] = hi[3];
  return r;
}

// ---------------- init ----------------
__global__ void k_init(u64* __restrict__ amin, u32* __restrict__ counts) {
  int t = blockIdx.x * 256 + threadIdx.x;
  if (t < NROWS) amin[t] = ~0ULL;
  if (t < NCODES) counts[t] = 0u;
}

// ---------------- inputs: fp32 -> fp8 + ||x||^2 per row ----------------
__global__ void k_cvtA(const float4* __restrict__ in, u32* __restrict__ outA,
                       float* __restrict__ rn) {
  int r = blockIdx.x;
  const float4* src = in + (size_t)r * (DIM / 4);
  u32* dst = outA + (size_t)r * (DIM / 4);
  float s = 0.0f;
#pragma unroll
  for (int q = 0; q < 4; ++q) {
    int j = q * 256 + threadIdx.x;
    float4 v = src[j];
    s += v.x * v.x + v.y * v.y + v.z * v.z + v.w * v.w;
    dst[j] = pack4(v);
  }
  s = waveRed(s);
  __shared__ float red[4];
  int wid = threadIdx.x >> 6, lane = threadIdx.x & 63;
  if (lane == 0) red[wid] = s;
  __syncthreads();
  if (threadIdx.x == 0) rn[r] = red[0] + red[1] + red[2] + red[3];
}

// ---------------- codebook: fp32 -> fp8*4096 + ||e||^2 ----------------
__global__ void k_cvtB(const float* __restrict__ cb, u32* __restrict__ Bb,
                       float* __restrict__ norms) {
  int row = blockIdx.x;
  const float4* src = (const float4*)(cb + (size_t)row * DIM);
  u32* dst = Bb + (size_t)row * (DIM / 4);
  float s = 0.0f;
#pragma unroll
  for (int q = 0; q < 4; ++q) {
    int j = q * 256 + threadIdx.x;
    float4 v = src[j];
    s += v.x * v.x + v.y * v.y + v.z * v.z + v.w * v.w;
    float4 sv;
    sv.x = v.x * 4096.0f; sv.y = v.y * 4096.0f;
    sv.z = v.z * 4096.0f; sv.w = v.w * 4096.0f;
    dst[j] = pack4(sv);
  }
  s = waveRed(s);
  __shared__ float red[4];
  int wid = threadIdx.x >> 6, lane = threadIdx.x & 63;
  if (lane == 0) red[wid] = s;
  __syncthreads();
  if (threadIdx.x == 0) norms[row] = red[0] + red[1] + red[2] + red[3];
}

// ---------------- MX-fp8 GEMM (x . e^T) + per-row argmin ----------------
// 256x256 tile, BK=128 fp8, 8 waves (2 M x 4 N), wave tile 128x64,
// 16x16x128 f8f6f4 MFMA with unit scales. Chunk swizzle (pre-swizzled
// global source, linear LDS dest, swizzled conflict-free reads).
// T4 counted vmcnt: [issue stage(t+1); vmcnt(8) drains only tile t's
// loads; bar; compute(t); bar] -- never drain the just-issued prefetch
// (R4/R5's vmcnt(0)-at-bottom bug). Last iteration peeled with vmcnt(0).
// T1 XCD-chunked swizzle: each XCD gets 64 consecutive work items =
// 2 B-panels (2 MB, L2-resident) x all bm.
__launch_bounds__(512, 2)
__global__ void k_gemm_argmin(const u8* __restrict__ A,
                              const u8* __restrict__ B,
                              const float* __restrict__ norms,
                              u64* __restrict__ amin) {
  __shared__ u8 As[2][BM * BK];   // 2 x 32 KiB
  __shared__ u8 Bs[2][BN * BK];   // 2 x 32 KiB

  // XCD-aware bijective remap (512 blocks = 8 XCD x 64)
  const int lb = blockIdx.y * gridDim.x + blockIdx.x;
  const int swz = (lb & 7) * 64 + (lb >> 3);
  const int bm = swz & 31;        // 32 M tiles
  const int bn = swz >> 5;        // 16 N tiles

  const int tid = threadIdx.x;
  const int w = tid >> 6;
  const int lane = tid & 63;
  const int wr = w >> 2, wc = w & 3;   // 2 x 4 wave grid
  const int g = lane >> 4, c = lane & 15;

  const size_t rowA0 = (size_t)bm * BM;
  const size_t rowB0 = (size_t)bn * BN;

  // stage-side swizzle: thread fills LDS chunk (tid&7) of row j*64+(tid>>3);
  // fetches global chunk (tid&7) ^ (row&7); row&7 == (tid>>3)&7 for all j.
  const int colb = (((tid & 7) ^ ((tid >> 3) & 7)) << 4);
  const int srow = tid >> 3;
  const u8* gA = A + rowA0 * DIM + colb;
  const u8* gB = B + rowB0 * DIM + colb;

  // read-side swizzle: fragment row&7 == c&7 for every m/n.
  const int colo = (((2 * g) ^ (c & 7)) << 4);
  const int cohi = (((2 * g + 1) ^ (c & 7)) << 4);

  f32x4 acc[8][4] = {};

#define STAGE(buf, kt_)                                                   \
  {                                                                       \
    _Pragma("unroll") for (int j = 0; j < 4; ++j) {                       \
      int o = j * 8192 + tid * 16;                                        \
      int row = j * 64 + srow;                                            \
      stage16(gA + (size_t)row * DIM + (size_t)(kt_)*BK,                  \
              (char*)As[buf] + o);                                        \
      stage16(gB + (size_t)row * DIM + (size_t)(kt_)*BK,                  \
              (char*)Bs[buf] + o);                                        \
    }                                                                     \
  }

#define COMPUTE(buf)                                                      \
  {                                                                       \
    i32x8 bv[4];                                                          \
    _Pragma("unroll") for (int n = 0; n < 4; ++n) {                       \
      int rown = (wc * 64 + n * 16 + c) * BK;                             \
      bv[n] = comb(*(const i32x4*)&Bs[buf][rown + colo],                  \
                   *(const i32x4*)&Bs[buf][rown + cohi]);                 \
    }                                                                     \
    _Pragma("unroll") for (int m = 0; m < 8; ++m) {                       \
      int rowm = (wr * 128 + m * 16 + c) * BK;                            \
      i32x8 af = comb(*(const i32x4*)&As[buf][rowm + colo],               \
                      *(const i32x4*)&As[buf][rowm + cohi]);              \
      _Pragma("unroll") for (int n = 0; n < 4; ++n)                       \
          acc[m][n] = __builtin_amdgcn_mfma_scale_f32_16x16x128_f8f6f4(   \
              af, bv[n], acc[m][n], 0, 0, 0, 0x7F7F7F7F, 0, 0x7F7F7F7F);  \
    }                                                                     \
  }

  // ---- prologue: stage tile 0 into buffer 0 ----
  STAGE(0, 0);

#pragma unroll 2
  for (int kt = 0; kt < KSTEPS - 1; ++kt) {
    const int cur = kt & 1;
    // issue next tile's stages (stay in flight across the wait below)
    STAGE(cur ^ 1, kt + 1);
    __builtin_amdgcn_sched_barrier(0);
    // drain ONLY tile kt's 8 loads; the 8 just-issued remain outstanding
    asm volatile("s_waitcnt vmcnt(8)" ::: "memory");
    __builtin_amdgcn_s_barrier();        // buf[cur] fully written, all waves
    __builtin_amdgcn_sched_barrier(0);
    COMPUTE(cur);
    __builtin_amdgcn_s_barrier();        // all reads of buf[cur] done
    __builtin_amdgcn_sched_barrier(0);
  }
  // peeled last iteration: nothing left to prefetch
  asm volatile("s_waitcnt vmcnt(0)" ::: "memory");
  __builtin_amdgcn_s_barrier();
  __builtin_amdgcn_sched_barrier(0);
  COMPUTE((KSTEPS - 1) & 1);

#undef STAGE
#undef COMPUTE

  // epilogue: d = ||e||^2 - (2/4096)*acc ; argmin over this block's 256 cols
  const int rowBase = bm * BM + wr * 128;
  const int colBase = bn * BN + wc * 64;
  float nr[4];
#pragma unroll
  for (int n = 0; n < 4; ++n) nr[n] = norms[colBase + n * 16 + c];

#pragma unroll
  for (int m = 0; m < 8; ++m) {
#pragma unroll
    for (int j = 0; j < 4; ++j) {
      u64 key = ~0ULL;
#pragma unroll
      for (int n = 0; n < 4; ++n) {
        float d = nr[n] - acc[m][n][j] * 4.8828125e-4f;   // 2/4096
        u32 u = __float_as_uint(d);
        u = (u & 0x80000000u) ? ~u : (u | 0x80000000u);
        u64 k2 = ((u64)u << 32) | (u32)(colBase + n * 16 + c);
        if (k2 < key) key = k2;
      }
#pragma unroll
      for (int off = 1; off < 16; off <<= 1) {
        u64 o = __shfl_xor(key, off);
        if (o < key) key = o;
      }
      if (c == 0) atomicMin(&amin[rowBase + m * 16 + g * 4 + j], key);
    }
  }
}

// ---------------- gather -> output + counts ----------------
__global__ void k_out(const float4* __restrict__ cb, const u64* __restrict__ amin,
                      float4* __restrict__ out, u32* __restrict__ counts) {
  int r = blockIdx.x;
  u32 idx = (u32)(amin[r] & 0xFFFFFFFFu);
  if (threadIdx.x == 0) atomicAdd(&counts[idx], 1u);
  const float4* crow = cb + (size_t)idx * (DIM / 4);
  float4* orow = out + (size_t)r * (DIM / 4);
#pragma unroll
  for (int q = 0; q < 4; ++q) {
    int j = q * 256 + threadIdx.x;
    orow[j] = crow[j];
  }
}

// ---------------- finalize: loss (from distances) + perplexity ----------------
__global__ void k_final(const u32* __restrict__ counts, const u64* __restrict__ amin,
                        const float* __restrict__ rn, float* __restrict__ out) {
  float acc = 0.0f;
  for (int r = threadIdx.x; r < NROWS; r += 256) {
    u32 u = (u32)(amin[r] >> 32);
    u32 b = (u & 0x80000000u) ? (u & 0x7FFFFFFFu) : ~u;  // undo sortable map
    acc += __uint_as_float(b) + rn[r];   // d_min + ||x||^2 = ||x - e||^2
  }
  float ent = 0.0f;
  for (int i = threadIdx.x; i < NCODES; i += 256) {
    float p = (float)counts[i] * (1.0f / (float)NROWS);
    ent -= p * logf(p + 1e-10f);
  }
  acc = waveRed(acc);
  ent = waveRed(ent);
  __shared__ float ra[4], re[4];
  int wid = threadIdx.x >> 6, lane = threadIdx.x & 63;
  if (lane == 0) { ra[wid] = acc; re[wid] = ent; }
  __syncthreads();
  if (threadIdx.x == 0) {
    float sse = ra[0] + ra[1] + ra[2] + ra[3];
    float e = re[0] + re[1] + re[2] + re[3];
    out[(size_t)NROWS * DIM] = 1.25f * sse * (1.0f / (float)((size_t)NROWS * DIM));
    out[(size_t)NROWS * DIM + 1] = expf(e);
  }
}

extern "C" void kernel_launch(void* const* d_in, const int* in_sizes, int n_in,
                              void* d_out, int out_size, void* d_ws, size_t ws_size,
                              hipStream_t stream) {
  const float* d_inputs = (const float*)d_in[0];
  const float* d_cb = (const float*)d_in[1];
  float* out = (float*)d_out;
  char* ws = (char*)d_ws;

  u8* A = (u8*)(ws + OFF_A);
  u8* B = (u8*)(ws + OFF_B);
  float* norms = (float*)(ws + OFF_NORMS);
  float* rn = (float*)(ws + OFF_RN);
  u64* amin = (u64*)(ws + OFF_AMIN);
  u32* counts = (u32*)(ws + OFF_COUNTS);

  k_init<<<32, 256, 0, stream>>>(amin, counts);
  k_cvtA<<<NROWS, 256, 0, stream>>>((const float4*)d_inputs, (u32*)A, rn);
  k_cvtB<<<NCODES, 256, 0, stream>>>(d_cb, (u32*)B, norms);
  dim3 grid(NROWS / BM, NCODES / BN);
  k_gemm_argmin<<<grid, 512, 0, stream>>>(A, B, norms, amin);
  k_out<<<NROWS, 256, 0, stream>>>((const float4*)d_cb, amin, (float4*)out, counts);
  k_final<<<1, 256, 0, stream>>>(counts, amin, rn, out);
}

// Round 7
// 1447.531 us; speedup vs baseline: 1.0007x; 1.0007x over previous
//
#include <hip/hip_runtime.h>
#include <hip/hip_bf16.h>
#include <stdint.h>

typedef unsigned int u32;
typedef unsigned char u8;
typedef unsigned long long u64;
typedef __attribute__((ext_vector_type(8))) int i32x8;
typedef __attribute__((ext_vector_type(4))) int i32x4;
typedef __attribute__((ext_vector_type(4))) float f32x4;

#define NROWS 8192    // 16*512
#define NCODES 4096
#define DIM 4096
#define BK 128
#define KSTEPS (DIM / BK)   // 32
#define BM 256
#define BN 256

// ---------------- workspace layout (bytes) ----------------
#define OFF_A      0UL
#define OFF_B      33554432UL
#define OFF_NORMS  50331648UL
#define OFF_RN     50348032UL
#define OFF_AMIN   50380800UL
#define OFF_COUNTS 50446336UL

__device__ __forceinline__ void stage16(const void* g, void* l) {
  __builtin_amdgcn_global_load_lds(
      (const __attribute__((address_space(1))) u32*)g,
      (__attribute__((address_space(3))) u32*)l, 16, 0, 0);
}

// float -> OCP e4m3fn, RNE, saturate to 448. Data is finite (no NaN path).
__device__ __forceinline__ u32 f2fp8(float f) {
  u32 u = __float_as_uint(f);
  u32 sign = (u >> 24) & 0x80u;
  u32 mag = u & 0x7FFFFFFFu;
  if (mag > 0x43E00000u) mag = 0x43E00000u;          // sat to 448
  u32 b;
  if (mag < 0x3C800000u) {                            // < 2^-6 : subnormal
    b = (u32)__float2int_rn(__uint_as_float(mag) * 512.0f);
  } else {
    u32 m = mag + 0x7FFFFu + ((mag >> 20) & 1u);      // RNE at 20-bit boundary
    u32 e = (m >> 23) - 127u;
    b = (((e + 7u) << 3) | ((m >> 20) & 7u)) & 0x7Fu;
  }
  return sign | b;
}

__device__ __forceinline__ u32 pack4(float4 v) {
  return f2fp8(v.x) | (f2fp8(v.y) << 8) | (f2fp8(v.z) << 16) | (f2fp8(v.w) << 24);
}

__device__ __forceinline__ float waveRed(float s) {
#pragma unroll
  for (int off = 32; off > 0; off >>= 1) s += __shfl_down(s, off);
  return s;
}

__device__ __forceinline__ i32x8 comb(i32x4 lo, i32x4 hi) {
  i32x8 r;
  r[0] = lo[0]; r[1] = lo[1]; r[2] = lo[2]; r[3] = lo[3];
  r[4] = hi[0]; r[5] = hi[1]; r[6] = hi[2]; r[7] = hi[3];
  return r;
}

// ---------------- init ----------------
__global__ void k_init(u64* __restrict__ amin, u32* __restrict__ counts) {
  int t = blockIdx.x * 256 + threadIdx.x;
  if (t < NROWS) amin[t] = ~0ULL;
  if (t < NCODES) counts[t] = 0u;
}

// ---------------- inputs: fp32 -> fp8 + ||x||^2 per row ----------------
__global__ void k_cvtA(const float4* __restrict__ in, u32* __restrict__ outA,
                       float* __restrict__ rn) {
  int r = blockIdx.x;
  const float4* src = in + (size_t)r * (DIM / 4);
  u32* dst = outA + (size_t)r * (DIM / 4);
  float s = 0.0f;
#pragma unroll
  for (int q = 0; q < 4; ++q) {
    int j = q * 256 + threadIdx.x;
    float4 v = src[j];
    s += v.x * v.x + v.y * v.y + v.z * v.z + v.w * v.w;
    dst[j] = pack4(v);
  }
  s = waveRed(s);
  __shared__ float red[4];
  int wid = threadIdx.x >> 6, lane = threadIdx.x & 63;
  if (lane == 0) red[wid] = s;
  __syncthreads();
  if (threadIdx.x == 0) rn[r] = red[0] + red[1] + red[2] + red[3];
}

// ---------------- codebook: fp32 -> fp8*4096 + ||e||^2 ----------------
__global__ void k_cvtB(const float* __restrict__ cb, u32* __restrict__ Bb,
                       float* __restrict__ norms) {
  int row = blockIdx.x;
  const float4* src = (const float4*)(cb + (size_t)row * DIM);
  u32* dst = Bb + (size_t)row * (DIM / 4);
  float s = 0.0f;
#pragma unroll
  for (int q = 0; q < 4; ++q) {
    int j = q * 256 + threadIdx.x;
    float4 v = src[j];
    s += v.x * v.x + v.y * v.y + v.z * v.z + v.w * v.w;
    float4 sv;
    sv.x = v.x * 4096.0f; sv.y = v.y * 4096.0f;
    sv.z = v.z * 4096.0f; sv.w = v.w * 4096.0f;
    dst[j] = pack4(sv);
  }
  s = waveRed(s);
  __shared__ float red[4];
  int wid = threadIdx.x >> 6, lane = threadIdx.x & 63;
  if (lane == 0) red[wid] = s;
  __syncthreads();
  if (threadIdx.x == 0) norms[row] = red[0] + red[1] + red[2] + red[3];
}

// ---------------- MX-fp8 GEMM (x . e^T) + per-row argmin ----------------
// 256x256 tile, BK=128 fp8, 8 waves (2 M x 4 N), wave tile 128x64,
// 16x16x128 f8f6f4 MFMA with unit scales. Chunk swizzle (pre-swizzled
// global source, linear LDS dest, swizzled conflict-free reads).
// T4 counted vmcnt: [issue stage(t+1); vmcnt(8) drains only tile t's
// loads; bar; compute(t); bar]. Last iteration peeled with vmcnt(0).
// T1 XCD-chunked swizzle: each XCD gets 64 consecutive work items.
// __launch_bounds__(512, 1): R6's (512,2) forced a 128-VGPR cap -> ~64
// regs spilled per K-step (1.77 GB scratch writes, 9x regression). This
// kernel needs ~200 VGPRs (acc alone is 128); 128 KB LDS limits us to
// 1 block/CU regardless, so ask for exactly that.
__launch_bounds__(512, 1)
__global__ void k_gemm_argmin(const u8* __restrict__ A,
                              const u8* __restrict__ B,
                              const float* __restrict__ norms,
                              u64* __restrict__ amin) {
  __shared__ u8 As[2][BM * BK];   // 2 x 32 KiB
  __shared__ u8 Bs[2][BN * BK];   // 2 x 32 KiB

  // XCD-aware bijective remap (512 blocks = 8 XCD x 64)
  const int lb = blockIdx.y * gridDim.x + blockIdx.x;
  const int swz = (lb & 7) * 64 + (lb >> 3);
  const int bm = swz & 31;        // 32 M tiles
  const int bn = swz >> 5;        // 16 N tiles

  const int tid = threadIdx.x;
  const int w = tid >> 6;
  const int lane = tid & 63;
  const int wr = w >> 2, wc = w & 3;   // 2 x 4 wave grid
  const int g = lane >> 4, c = lane & 15;

  const size_t rowA0 = (size_t)bm * BM;
  const size_t rowB0 = (size_t)bn * BN;

  // stage-side swizzle: thread fills LDS chunk (tid&7) of row j*64+(tid>>3);
  // fetches global chunk (tid&7) ^ (row&7); row&7 == (tid>>3)&7 for all j.
  const int colb = (((tid & 7) ^ ((tid >> 3) & 7)) << 4);
  const int srow = tid >> 3;
  const u8* gA = A + rowA0 * DIM + colb;
  const u8* gB = B + rowB0 * DIM + colb;

  // read-side swizzle: fragment row&7 == c&7 for every m/n.
  const int colo = (((2 * g) ^ (c & 7)) << 4);
  const int cohi = (((2 * g + 1) ^ (c & 7)) << 4);

  f32x4 acc[8][4] = {};

#define STAGE(buf, kt_)                                                   \
  {                                                                       \
    _Pragma("unroll") for (int j = 0; j < 4; ++j) {                       \
      int o = j * 8192 + tid * 16;                                        \
      int row = j * 64 + srow;                                            \
      stage16(gA + (size_t)row * DIM + (size_t)(kt_)*BK,                  \
              (char*)As[buf] + o);                                        \
      stage16(gB + (size_t)row * DIM + (size_t)(kt_)*BK,                  \
              (char*)Bs[buf] + o);                                        \
    }                                                                     \
  }

#define COMPUTE(buf)                                                      \
  {                                                                       \
    i32x8 bv[4];                                                          \
    _Pragma("unroll") for (int n = 0; n < 4; ++n) {                       \
      int rown = (wc * 64 + n * 16 + c) * BK;                             \
      bv[n] = comb(*(const i32x4*)&Bs[buf][rown + colo],                  \
                   *(const i32x4*)&Bs[buf][rown + cohi]);                 \
    }                                                                     \
    _Pragma("unroll") for (int m = 0; m < 8; ++m) {                       \
      int rowm = (wr * 128 + m * 16 + c) * BK;                            \
      i32x8 af = comb(*(const i32x4*)&As[buf][rowm + colo],               \
                      *(const i32x4*)&As[buf][rowm + cohi]);              \
      _Pragma("unroll") for (int n = 0; n < 4; ++n)                       \
          acc[m][n] = __builtin_amdgcn_mfma_scale_f32_16x16x128_f8f6f4(   \
              af, bv[n], acc[m][n], 0, 0, 0, 0x7F7F7F7F, 0, 0x7F7F7F7F);  \
    }                                                                     \
  }

  // ---- prologue: stage tile 0 into buffer 0 ----
  STAGE(0, 0);

#pragma unroll 2
  for (int kt = 0; kt < KSTEPS - 1; ++kt) {
    const int cur = kt & 1;
    // issue next tile's stages (stay in flight across the wait below)
    STAGE(cur ^ 1, kt + 1);
    __builtin_amdgcn_sched_barrier(0);
    // drain ONLY tile kt's 8 loads; the 8 just-issued remain outstanding
    asm volatile("s_waitcnt vmcnt(8)" ::: "memory");
    __builtin_amdgcn_s_barrier();        // buf[cur] fully written, all waves
    __builtin_amdgcn_sched_barrier(0);
    COMPUTE(cur);
    __builtin_amdgcn_s_barrier();        // all reads of buf[cur] done
    __builtin_amdgcn_sched_barrier(0);
  }
  // peeled last iteration: nothing left to prefetch
  asm volatile("s_waitcnt vmcnt(0)" ::: "memory");
  __builtin_amdgcn_s_barrier();
  __builtin_amdgcn_sched_barrier(0);
  COMPUTE((KSTEPS - 1) & 1);

#undef STAGE
#undef COMPUTE

  // epilogue: d = ||e||^2 - (2/4096)*acc ; argmin over this block's 256 cols
  const int rowBase = bm * BM + wr * 128;
  const int colBase = bn * BN + wc * 64;
  float nr[4];
#pragma unroll
  for (int n = 0; n < 4; ++n) nr[n] = norms[colBase + n * 16 + c];

#pragma unroll
  for (int m = 0; m < 8; ++m) {
#pragma unroll
    for (int j = 0; j < 4; ++j) {
      u64 key = ~0ULL;
#pragma unroll
      for (int n = 0; n < 4; ++n) {
        float d = nr[n] - acc[m][n][j] * 4.8828125e-4f;   // 2/4096
        u32 u = __float_as_uint(d);
        u = (u & 0x80000000u) ? ~u : (u | 0x80000000u);
        u64 k2 = ((u64)u << 32) | (u32)(colBase + n * 16 + c);
        if (k2 < key) key = k2;
      }
#pragma unroll
      for (int off = 1; off < 16; off <<= 1) {
        u64 o = __shfl_xor(key, off);
        if (o < key) key = o;
      }
      if (c == 0) atomicMin(&amin[rowBase + m * 16 + g * 4 + j], key);
    }
  }
}

// ---------------- gather -> output + counts ----------------
__global__ void k_out(const float4* __restrict__ cb, const u64* __restrict__ amin,
                      float4* __restrict__ out, u32* __restrict__ counts) {
  int r = blockIdx.x;
  u32 idx = (u32)(amin[r] & 0xFFFFFFFFu);
  if (threadIdx.x == 0) atomicAdd(&counts[idx], 1u);
  const float4* crow = cb + (size_t)idx * (DIM / 4);
  float4* orow = out + (size_t)r * (DIM / 4);
#pragma unroll
  for (int q = 0; q < 4; ++q) {
    int j = q * 256 + threadIdx.x;
    orow[j] = crow[j];
  }
}

// ---------------- finalize: loss (from distances) + perplexity ----------------
__global__ void k_final(const u32* __restrict__ counts, const u64* __restrict__ amin,
                        const float* __restrict__ rn, float* __restrict__ out) {
  float acc = 0.0f;
  for (int r = threadIdx.x; r < NROWS; r += 256) {
    u32 u = (u32)(amin[r] >> 32);
    u32 b = (u & 0x80000000u) ? (u & 0x7FFFFFFFu) : ~u;  // undo sortable map
    acc += __uint_as_float(b) + rn[r];   // d_min + ||x||^2 = ||x - e||^2
  }
  float ent = 0.0f;
  for (int i = threadIdx.x; i < NCODES; i += 256) {
    float p = (float)counts[i] * (1.0f / (float)NROWS);
    ent -= p * logf(p + 1e-10f);
  }
  acc = waveRed(acc);
  ent = waveRed(ent);
  __shared__ float ra[4], re[4];
  int wid = threadIdx.x >> 6, lane = threadIdx.x & 63;
  if (lane == 0) { ra[wid] = acc; re[wid] = ent; }
  __syncthreads();
  if (threadIdx.x == 0) {
    float sse = ra[0] + ra[1] + ra[2] + ra[3];
    float e = re[0] + re[1] + re[2] + re[3];
    out[(size_t)NROWS * DIM] = 1.25f * sse * (1.0f / (float)((size_t)NROWS * DIM));
    out[(size_t)NROWS * DIM + 1] = expf(e);
  }
}

extern "C" void kernel_launch(void* const* d_in, const int* in_sizes, int n_in,
                              void* d_out, int out_size, void* d_ws, size_t ws_size,
                              hipStream_t stream) {
  const float* d_inputs = (const float*)d_in[0];
  const float* d_cb = (const float*)d_in[1];
  float* out = (float*)d_out;
  char* ws = (char*)d_ws;

  u8* A = (u8*)(ws + OFF_A);
  u8* B = (u8*)(ws + OFF_B);
  float* norms = (float*)(ws + OFF_NORMS);
  float* rn = (float*)(ws + OFF_RN);
  u64* amin = (u64*)(ws + OFF_AMIN);
  u32* counts = (u32*)(ws + OFF_COUNTS);

  k_init<<<32, 256, 0, stream>>>(amin, counts);
  k_cvtA<<<NROWS, 256, 0, stream>>>((const float4*)d_inputs, (u32*)A, rn);
  k_cvtB<<<NCODES, 256, 0, stream>>>(d_cb, (u32*)B, norms);
  dim3 grid(NROWS / BM, NCODES / BN);
  k_gemm_argmin<<<grid, 512, 0, stream>>>(A, B, norms, amin);
  k_out<<<NROWS, 256, 0, stream>>>((const float4*)d_cb, amin, (float4*)out, counts);
  k_final<<<1, 256, 0, stream>>>(counts, amin, rn, out);
}

// Round 8
// 270.921 us; speedup vs baseline: 5.3466x; 5.3430x over previous
//
#include <hip/hip_runtime.h>
#include <hip/hip_bf16.h>
#include <stdint.h>

typedef unsigned int u32;
typedef unsigned char u8;
typedef unsigned long long u64;
typedef __attribute__((ext_vector_type(8))) int i32x8;
typedef __attribute__((ext_vector_type(4))) int i32x4;
typedef __attribute__((ext_vector_type(4))) float f32x4;

#define NROWS 8192    // 16*512
#define NCODES 4096
#define DIM 4096
#define BK 128
#define KSTEPS (DIM / BK)   // 32
#define BM 256
#define BN 256

// ---------------- workspace layout (bytes) ----------------
#define OFF_A      0UL
#define OFF_B      33554432UL
#define OFF_NORMS  50331648UL
#define OFF_RN     50348032UL
#define OFF_AMIN   50380800UL
#define OFF_COUNTS 50446336UL

__device__ __forceinline__ void stage16(const void* g, void* l) {
  __builtin_amdgcn_global_load_lds(
      (const __attribute__((address_space(1))) u32*)g,
      (__attribute__((address_space(3))) u32*)l, 16, 0, 0);
}

// float -> OCP e4m3fn, RNE, saturate to 448. Data is finite (no NaN path).
__device__ __forceinline__ u32 f2fp8(float f) {
  u32 u = __float_as_uint(f);
  u32 sign = (u >> 24) & 0x80u;
  u32 mag = u & 0x7FFFFFFFu;
  if (mag > 0x43E00000u) mag = 0x43E00000u;          // sat to 448
  u32 b;
  if (mag < 0x3C800000u) {                            // < 2^-6 : subnormal
    b = (u32)__float2int_rn(__uint_as_float(mag) * 512.0f);
  } else {
    u32 m = mag + 0x7FFFFu + ((mag >> 20) & 1u);      // RNE at 20-bit boundary
    u32 e = (m >> 23) - 127u;
    b = (((e + 7u) << 3) | ((m >> 20) & 7u)) & 0x7Fu;
  }
  return sign | b;
}

__device__ __forceinline__ u32 pack4(float4 v) {
  return f2fp8(v.x) | (f2fp8(v.y) << 8) | (f2fp8(v.z) << 16) | (f2fp8(v.w) << 24);
}

__device__ __forceinline__ float waveRed(float s) {
#pragma unroll
  for (int off = 32; off > 0; off >>= 1) s += __shfl_down(s, off);
  return s;
}

__device__ __forceinline__ i32x8 comb(i32x4 lo, i32x4 hi) {
  i32x8 r;
  r[0] = lo[0]; r[1] = lo[1]; r[2] = lo[2]; r[3] = lo[3];
  r[4] = hi[0]; r[5] = hi[1]; r[6] = hi[2]; r[7] = hi[3];
  return r;
}

// ---------------- init ----------------
__global__ void k_init(u64* __restrict__ amin, u32* __restrict__ counts) {
  int t = blockIdx.x * 256 + threadIdx.x;
  if (t < NROWS) amin[t] = ~0ULL;
  if (t < NCODES) counts[t] = 0u;
}

// ---------------- inputs: fp32 -> fp8 + ||x||^2 per row ----------------
__global__ void k_cvtA(const float4* __restrict__ in, u32* __restrict__ outA,
                       float* __restrict__ rn) {
  int r = blockIdx.x;
  const float4* src = in + (size_t)r * (DIM / 4);
  u32* dst = outA + (size_t)r * (DIM / 4);
  float s = 0.0f;
#pragma unroll
  for (int q = 0; q < 4; ++q) {
    int j = q * 256 + threadIdx.x;
    float4 v = src[j];
    s += v.x * v.x + v.y * v.y + v.z * v.z + v.w * v.w;
    dst[j] = pack4(v);
  }
  s = waveRed(s);
  __shared__ float red[4];
  int wid = threadIdx.x >> 6, lane = threadIdx.x & 63;
  if (lane == 0) red[wid] = s;
  __syncthreads();
  if (threadIdx.x == 0) rn[r] = red[0] + red[1] + red[2] + red[3];
}

// ---------------- codebook: fp32 -> fp8*4096 + ||e||^2 ----------------
__global__ void k_cvtB(const float* __restrict__ cb, u32* __restrict__ Bb,
                       float* __restrict__ norms) {
  int row = blockIdx.x;
  const float4* src = (const float4*)(cb + (size_t)row * DIM);
  u32* dst = Bb + (size_t)row * (DIM / 4);
  float s = 0.0f;
#pragma unroll
  for (int q = 0; q < 4; ++q) {
    int j = q * 256 + threadIdx.x;
    float4 v = src[j];
    s += v.x * v.x + v.y * v.y + v.z * v.z + v.w * v.w;
    float4 sv;
    sv.x = v.x * 4096.0f; sv.y = v.y * 4096.0f;
    sv.z = v.z * 4096.0f; sv.w = v.w * 4096.0f;
    dst[j] = pack4(sv);
  }
  s = waveRed(s);
  __shared__ float red[4];
  int wid = threadIdx.x >> 6, lane = threadIdx.x & 63;
  if (lane == 0) red[wid] = s;
  __syncthreads();
  if (threadIdx.x == 0) norms[row] = red[0] + red[1] + red[2] + red[3];
}

// ---------------- MX-fp8 GEMM (x . e^T) + per-row argmin ----------------
// 256x256 tile, BK=128 fp8, 8 waves (2 M x 4 N), wave tile 128x64,
// 16x16x128 f8f6f4 MFMA with unit scales. Chunk swizzle (pre-swizzled
// global source, linear LDS dest, swizzled conflict-free reads).
// T4 counted vmcnt with FULLY STATIC double-buffering: manual 2-K-step
// loop body with literal buffer indices, even trip count (15) + static
// epilogue. R6/R7's dynamic-cur + odd-trip unroll-2 remainder caused the
// whole acc[8][4] to spill to scratch every K-step (1.77 GB writes,
// 32 KB/wave/step = 128 VGPRs round-tripped; 9x regression). All buffer
// indices here are compile-time literals so MFMA accumulators can stay
// in AGPRs.
__launch_bounds__(512, 1)
__global__ void k_gemm_argmin(const u8* __restrict__ A,
                              const u8* __restrict__ B,
                              const float* __restrict__ norms,
                              u64* __restrict__ amin) {
  __shared__ u8 As[2][BM * BK];   // 2 x 32 KiB
  __shared__ u8 Bs[2][BN * BK];   // 2 x 32 KiB

  // XCD-aware bijective remap (512 blocks = 8 XCD x 64)
  const int lb = blockIdx.y * gridDim.x + blockIdx.x;
  const int swz = (lb & 7) * 64 + (lb >> 3);
  const int bm = swz & 31;        // 32 M tiles
  const int bn = swz >> 5;        // 16 N tiles

  const int tid = threadIdx.x;
  const int w = tid >> 6;
  const int lane = tid & 63;
  const int wr = w >> 2, wc = w & 3;   // 2 x 4 wave grid
  const int g = lane >> 4, c = lane & 15;

  const size_t rowA0 = (size_t)bm * BM;
  const size_t rowB0 = (size_t)bn * BN;

  // stage-side swizzle: thread fills LDS chunk (tid&7) of row j*64+(tid>>3);
  // fetches global chunk (tid&7) ^ (row&7); row&7 == (tid>>3)&7 for all j.
  const int colb = (((tid & 7) ^ ((tid >> 3) & 7)) << 4);
  const int srow = tid >> 3;
  const u8* gA = A + rowA0 * DIM + colb;
  const u8* gB = B + rowB0 * DIM + colb;

  // read-side swizzle: fragment row&7 == c&7 for every m/n.
  const int colo = (((2 * g) ^ (c & 7)) << 4);
  const int cohi = (((2 * g + 1) ^ (c & 7)) << 4);

  f32x4 acc[8][4] = {};

#define STAGE(buf, kt_)                                                   \
  {                                                                       \
    _Pragma("unroll") for (int j = 0; j < 4; ++j) {                       \
      int o = j * 8192 + tid * 16;                                        \
      int row = j * 64 + srow;                                            \
      stage16(gA + (size_t)row * DIM + (size_t)(kt_)*BK,                  \
              (char*)As[buf] + o);                                        \
      stage16(gB + (size_t)row * DIM + (size_t)(kt_)*BK,                  \
              (char*)Bs[buf] + o);                                        \
    }                                                                     \
  }

#define COMPUTE(buf)                                                      \
  {                                                                       \
    i32x8 bv[4];                                                          \
    _Pragma("unroll") for (int n = 0; n < 4; ++n) {                       \
      int rown = (wc * 64 + n * 16 + c) * BK;                             \
      bv[n] = comb(*(const i32x4*)&Bs[buf][rown + colo],                  \
                   *(const i32x4*)&Bs[buf][rown + cohi]);                 \
    }                                                                     \
    _Pragma("unroll") for (int m = 0; m < 8; ++m) {                       \
      int rowm = (wr * 128 + m * 16 + c) * BK;                            \
      i32x8 af = comb(*(const i32x4*)&As[buf][rowm + colo],               \
                      *(const i32x4*)&As[buf][rowm + cohi]);              \
      _Pragma("unroll") for (int n = 0; n < 4; ++n)                       \
          acc[m][n] = __builtin_amdgcn_mfma_scale_f32_16x16x128_f8f6f4(   \
              af, bv[n], acc[m][n], 0, 0, 0, 0x7F7F7F7F, 0, 0x7F7F7F7F);  \
    }                                                                     \
  }

#define WAIT8_BAR()                                          \
  asm volatile("s_waitcnt vmcnt(8)" ::: "memory");           \
  __builtin_amdgcn_s_barrier();                              \
  __builtin_amdgcn_sched_barrier(0);

#define BAR()                                                \
  __builtin_amdgcn_s_barrier();                              \
  __builtin_amdgcn_sched_barrier(0);

  // ---- prologue: stage tile 0 into buffer 0 (8 loads in flight) ----
  STAGE(0, 0);

#pragma unroll 1
  for (int kt2 = 0; kt2 < 15; ++kt2) {
    STAGE(1, 2 * kt2 + 1);        // outstanding: 16
    WAIT8_BAR();                  // tile 2*kt2 landed in buf0; prefetch in flight
    COMPUTE(0);                   // tile 2*kt2
    BAR();                        // all reads of buf0 done -> safe to restage
    STAGE(0, 2 * kt2 + 2);        // outstanding: 16
    WAIT8_BAR();                  // tile 2*kt2+1 landed in buf1
    COMPUTE(1);                   // tile 2*kt2+1
    BAR();                        // all reads of buf1 done
  }
  // ---- static epilogue: tiles 30 (buf0, already staged) and 31 ----
  STAGE(1, 31);                   // outstanding: 16
  WAIT8_BAR();                    // tile 30 landed
  COMPUTE(0);                     // tile 30
  asm volatile("s_waitcnt vmcnt(0)" ::: "memory");
  __builtin_amdgcn_s_barrier();   // every wave's tile-31 writes landed
  __builtin_amdgcn_sched_barrier(0);
  COMPUTE(1);                     // tile 31

#undef STAGE
#undef COMPUTE
#undef WAIT8_BAR
#undef BAR

  // epilogue: d = ||e||^2 - (2/4096)*acc ; argmin over this block's 256 cols
  const int rowBase = bm * BM + wr * 128;
  const int colBase = bn * BN + wc * 64;
  float nr[4];
#pragma unroll
  for (int n = 0; n < 4; ++n) nr[n] = norms[colBase + n * 16 + c];

#pragma unroll
  for (int m = 0; m < 8; ++m) {
#pragma unroll
    for (int j = 0; j < 4; ++j) {
      u64 key = ~0ULL;
#pragma unroll
      for (int n = 0; n < 4; ++n) {
        float d = nr[n] - acc[m][n][j] * 4.8828125e-4f;   // 2/4096
        u32 u = __float_as_uint(d);
        u = (u & 0x80000000u) ? ~u : (u | 0x80000000u);
        u64 k2 = ((u64)u << 32) | (u32)(colBase + n * 16 + c);
        if (k2 < key) key = k2;
      }
#pragma unroll
      for (int off = 1; off < 16; off <<= 1) {
        u64 o = __shfl_xor(key, off);
        if (o < key) key = o;
      }
      if (c == 0) atomicMin(&amin[rowBase + m * 16 + g * 4 + j], key);
    }
  }
}

// ---------------- gather -> output + counts ----------------
__global__ void k_out(const float4* __restrict__ cb, const u64* __restrict__ amin,
                      float4* __restrict__ out, u32* __restrict__ counts) {
  int r = blockIdx.x;
  u32 idx = (u32)(amin[r] & 0xFFFFFFFFu);
  if (threadIdx.x == 0) atomicAdd(&counts[idx], 1u);
  const float4* crow = cb + (size_t)idx * (DIM / 4);
  float4* orow = out + (size_t)r * (DIM / 4);
#pragma unroll
  for (int q = 0; q < 4; ++q) {
    int j = q * 256 + threadIdx.x;
    orow[j] = crow[j];
  }
}

// ---------------- finalize: loss (from distances) + perplexity ----------------
__global__ void k_final(const u32* __restrict__ counts, const u64* __restrict__ amin,
                        const float* __restrict__ rn, float* __restrict__ out) {
  float acc = 0.0f;
  for (int r = threadIdx.x; r < NROWS; r += 256) {
    u32 u = (u32)(amin[r] >> 32);
    u32 b = (u & 0x80000000u) ? (u & 0x7FFFFFFFu) : ~u;  // undo sortable map
    acc += __uint_as_float(b) + rn[r];   // d_min + ||x||^2 = ||x - e||^2
  }
  float ent = 0.0f;
  for (int i = threadIdx.x; i < NCODES; i += 256) {
    float p = (float)counts[i] * (1.0f / (float)NROWS);
    ent -= p * logf(p + 1e-10f);
  }
  acc = waveRed(acc);
  ent = waveRed(ent);
  __shared__ float ra[4], re[4];
  int wid = threadIdx.x >> 6, lane = threadIdx.x & 63;
  if (lane == 0) { ra[wid] = acc; re[wid] = ent; }
  __syncthreads();
  if (threadIdx.x == 0) {
    float sse = ra[0] + ra[1] + ra[2] + ra[3];
    float e = re[0] + re[1] + re[2] + re[3];
    out[(size_t)NROWS * DIM] = 1.25f * sse * (1.0f / (float)((size_t)NROWS * DIM));
    out[(size_t)NROWS * DIM + 1] = expf(e);
  }
}

extern "C" void kernel_launch(void* const* d_in, const int* in_sizes, int n_in,
                              void* d_out, int out_size, void* d_ws, size_t ws_size,
                              hipStream_t stream) {
  const float* d_inputs = (const float*)d_in[0];
  const float* d_cb = (const float*)d_in[1];
  float* out = (float*)d_out;
  char* ws = (char*)d_ws;

  u8* A = (u8*)(ws + OFF_A);
  u8* B = (u8*)(ws + OFF_B);
  float* norms = (float*)(ws + OFF_NORMS);
  float* rn = (float*)(ws + OFF_RN);
  u64* amin = (u64*)(ws + OFF_AMIN);
  u32* counts = (u32*)(ws + OFF_COUNTS);

  k_init<<<32, 256, 0, stream>>>(amin, counts);
  k_cvtA<<<NROWS, 256, 0, stream>>>((const float4*)d_inputs, (u32*)A, rn);
  k_cvtB<<<NCODES, 256, 0, stream>>>(d_cb, (u32*)B, norms);
  dim3 grid(NROWS / BM, NCODES / BN);
  k_gemm_argmin<<<grid, 512, 0, stream>>>(A, B, norms, amin);
  k_out<<<NROWS, 256, 0, stream>>>((const float4*)d_cb, amin, (float4*)out, counts);
  k_final<<<1, 256, 0, stream>>>(counts, amin, rn, out);
}

// Round 9
// 267.381 us; speedup vs baseline: 5.4174x; 1.0132x over previous
//
#include <hip/hip_runtime.h>
#include <hip/hip_bf16.h>
#include <stdint.h>

typedef unsigned int u32;
typedef unsigned char u8;
typedef unsigned long long u64;
typedef __attribute__((ext_vector_type(8))) int i32x8;
typedef __attribute__((ext_vector_type(4))) int i32x4;
typedef __attribute__((ext_vector_type(4))) float f32x4;

#define NROWS 8192    // 16*512
#define NCODES 4096
#define DIM 4096
#define BK 128
#define KSTEPS (DIM / BK)   // 32
#define BM 256
#define BN 256

// ---------------- workspace layout (bytes) ----------------
#define OFF_A      0UL
#define OFF_B      33554432UL
#define OFF_NORMS  50331648UL
#define OFF_RN     50348032UL
#define OFF_AMIN   50380800UL
#define OFF_COUNTS 50446336UL

__device__ __forceinline__ void stage16(const void* g, void* l) {
  __builtin_amdgcn_global_load_lds(
      (const __attribute__((address_space(1))) u32*)g,
      (__attribute__((address_space(3))) u32*)l, 16, 0, 0);
}

// float -> OCP e4m3fn, RNE, saturate to 448. Data is finite (no NaN path).
__device__ __forceinline__ u32 f2fp8(float f) {
  u32 u = __float_as_uint(f);
  u32 sign = (u >> 24) & 0x80u;
  u32 mag = u & 0x7FFFFFFFu;
  if (mag > 0x43E00000u) mag = 0x43E00000u;          // sat to 448
  u32 b;
  if (mag < 0x3C800000u) {                            // < 2^-6 : subnormal
    b = (u32)__float2int_rn(__uint_as_float(mag) * 512.0f);
  } else {
    u32 m = mag + 0x7FFFFu + ((mag >> 20) & 1u);      // RNE at 20-bit boundary
    u32 e = (m >> 23) - 127u;
    b = (((e + 7u) << 3) | ((m >> 20) & 7u)) & 0x7Fu;
  }
  return sign | b;
}

__device__ __forceinline__ u32 pack4(float4 v) {
  return f2fp8(v.x) | (f2fp8(v.y) << 8) | (f2fp8(v.z) << 16) | (f2fp8(v.w) << 24);
}

__device__ __forceinline__ float waveRed(float s) {
#pragma unroll
  for (int off = 32; off > 0; off >>= 1) s += __shfl_down(s, off);
  return s;
}

__device__ __forceinline__ i32x8 comb(i32x4 lo, i32x4 hi) {
  i32x8 r;
  r[0] = lo[0]; r[1] = lo[1]; r[2] = lo[2]; r[3] = lo[3];
  r[4] = hi[0]; r[5] = hi[1]; r[6] = hi[2]; r[7] = hi[3];
  return r;
}

// ---------------- inputs: fp32 -> fp8 + ||x||^2 per row (+ amin init) -------
__global__ void k_cvtA(const float4* __restrict__ in, u32* __restrict__ outA,
                       float* __restrict__ rn, u64* __restrict__ amin) {
  int r = blockIdx.x;
  if (threadIdx.x == 64) amin[r] = ~0ULL;   // fold k_init: one launch fewer
  const float4* src = in + (size_t)r * (DIM / 4);
  u32* dst = outA + (size_t)r * (DIM / 4);
  float s = 0.0f;
#pragma unroll
  for (int q = 0; q < 4; ++q) {
    int j = q * 256 + threadIdx.x;
    float4 v = src[j];
    s += v.x * v.x + v.y * v.y + v.z * v.z + v.w * v.w;
    dst[j] = pack4(v);
  }
  s = waveRed(s);
  __shared__ float red[4];
  int wid = threadIdx.x >> 6, lane = threadIdx.x & 63;
  if (lane == 0) red[wid] = s;
  __syncthreads();
  if (threadIdx.x == 0) rn[r] = red[0] + red[1] + red[2] + red[3];
}

// ---------------- codebook: fp32 -> fp8*4096 + ||e||^2 (+ counts init) ------
__global__ void k_cvtB(const float* __restrict__ cb, u32* __restrict__ Bb,
                       float* __restrict__ norms, u32* __restrict__ counts) {
  int row = blockIdx.x;
  if (threadIdx.x == 64) counts[row] = 0u;
  const float4* src = (const float4*)(cb + (size_t)row * DIM);
  u32* dst = Bb + (size_t)row * (DIM / 4);
  float s = 0.0f;
#pragma unroll
  for (int q = 0; q < 4; ++q) {
    int j = q * 256 + threadIdx.x;
    float4 v = src[j];
    s += v.x * v.x + v.y * v.y + v.z * v.z + v.w * v.w;
    float4 sv;
    sv.x = v.x * 4096.0f; sv.y = v.y * 4096.0f;
    sv.z = v.z * 4096.0f; sv.w = v.w * 4096.0f;
    dst[j] = pack4(sv);
  }
  s = waveRed(s);
  __shared__ float red[4];
  int wid = threadIdx.x >> 6, lane = threadIdx.x & 63;
  if (lane == 0) red[wid] = s;
  __syncthreads();
  if (threadIdx.x == 0) norms[row] = red[0] + red[1] + red[2] + red[3];
}

// ---------------- MX-fp8 GEMM (x . e^T) + per-row argmin ----------------
// 256x256 tile, BK=128 fp8, 8 waves (2 M x 4 N), wave tile 128x64,
// 16x16x128 f8f6f4 MFMA with unit scales. Chunk swizzle (pre-swizzled
// global source, linear LDS dest, swizzled conflict-free reads).
// T4 counted vmcnt, fully static double-buffering (literal buffer ids,
// even trip structure) -- R6/R7's dynamic-cur remainder spilled all of
// acc (1.77 GB scratch traffic).
// NO XCD swizzle: R8 measured it TRIPLES L2-miss traffic (98->315 MB)
// because each XCD then streams all 32 A-tiles through a 4 MB L2 per
// bn-column; default dispatch order has better A temporal reuse.
// Register budget: 1 block/CU x 8 waves = 2 waves/SIMD -> 256 unified
// regs/wave; acc[8][4] = 128 AGPR -> everything else must fit in 128.
__launch_bounds__(512, 1)
__global__ void k_gemm_argmin(const u8* __restrict__ A,
                              const u8* __restrict__ B,
                              const float* __restrict__ norms,
                              u64* __restrict__ amin) {
  __shared__ u8 As[2][BM * BK];   // 2 x 32 KiB
  __shared__ u8 Bs[2][BN * BK];   // 2 x 32 KiB

  const int bm = blockIdx.x;
  const int bn = blockIdx.y;

  const int tid = threadIdx.x;
  const int w = tid >> 6;
  const int lane = tid & 63;
  const int wr = w >> 2, wc = w & 3;   // 2 x 4 wave grid
  const int g = lane >> 4, c = lane & 15;

  const size_t rowA0 = (size_t)bm * BM;
  const size_t rowB0 = (size_t)bn * BN;

  // stage-side swizzle: thread fills LDS chunk (tid&7) of row j*64+(tid>>3);
  // fetches global chunk (tid&7) ^ (row&7); row&7 == (tid>>3)&7 for all j.
  const int colb = (((tid & 7) ^ ((tid >> 3) & 7)) << 4);
  const int srow = tid >> 3;
  const u8* gA = A + rowA0 * DIM + colb;
  const u8* gB = B + rowB0 * DIM + colb;

  // read-side swizzle: fragment row&7 == c&7 for every m/n; the two 16B
  // halves of a 32B window sit at chunk colo and colo^16.
  const int colo = (((2 * g) ^ (c & 7)) << 4);

  f32x4 acc[8][4] = {};

#define STAGE(buf, kt_)                                                   \
  {                                                                       \
    _Pragma("unroll") for (int j = 0; j < 4; ++j) {                       \
      int o = j * 8192 + tid * 16;                                        \
      int row = j * 64 + srow;                                            \
      stage16(gA + (size_t)row * DIM + (size_t)(kt_)*BK,                  \
              (char*)As[buf] + o);                                        \
      stage16(gB + (size_t)row * DIM + (size_t)(kt_)*BK,                  \
              (char*)Bs[buf] + o);                                        \
    }                                                                     \
  }

#define COMPUTE(buf)                                                      \
  {                                                                       \
    i32x8 bv[4];                                                          \
    _Pragma("unroll") for (int n = 0; n < 4; ++n) {                       \
      int rown = (wc * 64 + n * 16 + c) * BK;                             \
      bv[n] = comb(*(const i32x4*)&Bs[buf][rown + colo],                  \
                   *(const i32x4*)&Bs[buf][rown + (colo ^ 16)]);          \
    }                                                                     \
    _Pragma("unroll") for (int m = 0; m < 8; ++m) {                       \
      int rowm = (wr * 128 + m * 16 + c) * BK;                            \
      i32x8 af = comb(*(const i32x4*)&As[buf][rowm + colo],               \
                      *(const i32x4*)&As[buf][rowm + (colo ^ 16)]);       \
      _Pragma("unroll") for (int n = 0; n < 4; ++n)                       \
          acc[m][n] = __builtin_amdgcn_mfma_scale_f32_16x16x128_f8f6f4(   \
              af, bv[n], acc[m][n], 0, 0, 0, 0x7F7F7F7F, 0, 0x7F7F7F7F);  \
    }                                                                     \
  }

#define WAIT8_BAR()                                          \
  asm volatile("s_waitcnt vmcnt(8)" ::: "memory");           \
  __builtin_amdgcn_s_barrier();                              \
  __builtin_amdgcn_sched_barrier(0);

  // ---- prologue: stage tile 0 into buffer 0 (8 loads in flight) ----
  STAGE(0, 0);

#pragma unroll 1
  for (int kt2 = 0; kt2 < 15; ++kt2) {
    STAGE(1, 2 * kt2 + 1);        // outstanding: 16
    WAIT8_BAR();                  // tile 2*kt2 landed in buf0; prefetch in flight
    COMPUTE(0);                   // tile 2*kt2
    __builtin_amdgcn_s_barrier(); // all reads of buf0 done -> safe to restage
    STAGE(0, 2 * kt2 + 2);        // outstanding: 16
    WAIT8_BAR();                  // tile 2*kt2+1 landed in buf1
    COMPUTE(1);                   // tile 2*kt2+1
    __builtin_amdgcn_s_barrier(); // all reads of buf1 done
  }
  // ---- static epilogue: tiles 30 (buf0, already staged) and 31 ----
  STAGE(1, 31);                   // outstanding: 16
  WAIT8_BAR();                    // tile 30 landed
  COMPUTE(0);                     // tile 30
  asm volatile("s_waitcnt vmcnt(0)" ::: "memory");
  __builtin_amdgcn_s_barrier();   // every wave's tile-31 writes landed
  __builtin_amdgcn_sched_barrier(0);
  COMPUTE(1);                     // tile 31

#undef STAGE
#undef COMPUTE
#undef WAIT8_BAR

  // epilogue: d = ||e||^2 - (2/4096)*acc ; argmin over this block's 256 cols
  const int rowBase = bm * BM + wr * 128;
  const int colBase = bn * BN + wc * 64;
  float nr[4];
#pragma unroll
  for (int n = 0; n < 4; ++n) nr[n] = norms[colBase + n * 16 + c];

#pragma unroll
  for (int m = 0; m < 8; ++m) {
#pragma unroll
    for (int j = 0; j < 4; ++j) {
      u64 key = ~0ULL;
#pragma unroll
      for (int n = 0; n < 4; ++n) {
        float d = nr[n] - acc[m][n][j] * 4.8828125e-4f;   // 2/4096
        u32 u = __float_as_uint(d);
        u = (u & 0x80000000u) ? ~u : (u | 0x80000000u);
        u64 k2 = ((u64)u << 32) | (u32)(colBase + n * 16 + c);
        if (k2 < key) key = k2;
      }
#pragma unroll
      for (int off = 1; off < 16; off <<= 1) {
        u64 o = __shfl_xor(key, off);
        if (o < key) key = o;
      }
      if (c == 0) atomicMin(&amin[rowBase + m * 16 + g * 4 + j], key);
    }
  }
}

// ---------------- gather -> output + counts ----------------
__global__ void k_out(const float4* __restrict__ cb, const u64* __restrict__ amin,
                      float4* __restrict__ out, u32* __restrict__ counts) {
  int r = blockIdx.x;
  u32 idx = (u32)(amin[r] & 0xFFFFFFFFu);
  if (threadIdx.x == 0) atomicAdd(&counts[idx], 1u);
  const float4* crow = cb + (size_t)idx * (DIM / 4);
  float4* orow = out + (size_t)r * (DIM / 4);
#pragma unroll
  for (int q = 0; q < 4; ++q) {
    int j = q * 256 + threadIdx.x;
    orow[j] = crow[j];
  }
}

// ---------------- finalize: loss (from distances) + perplexity ----------------
__global__ void k_final(const u32* __restrict__ counts, const u64* __restrict__ amin,
                        const float* __restrict__ rn, float* __restrict__ out) {
  float acc = 0.0f;
  for (int r = threadIdx.x; r < NROWS; r += 256) {
    u32 u = (u32)(amin[r] >> 32);
    u32 b = (u & 0x80000000u) ? (u & 0x7FFFFFFFu) : ~u;  // undo sortable map
    acc += __uint_as_float(b) + rn[r];   // d_min + ||x||^2 = ||x - e||^2
  }
  float ent = 0.0f;
  for (int i = threadIdx.x; i < NCODES; i += 256) {
    float p = (float)counts[i] * (1.0f / (float)NROWS);
    ent -= p * logf(p + 1e-10f);
  }
  acc = waveRed(acc);
  ent = waveRed(ent);
  __shared__ float ra[4], re[4];
  int wid = threadIdx.x >> 6, lane = threadIdx.x & 63;
  if (lane == 0) { ra[wid] = acc; re[wid] = ent; }
  __syncthreads();
  if (threadIdx.x == 0) {
    float sse = ra[0] + ra[1] + ra[2] + ra[3];
    float e = re[0] + re[1] + re[2] + re[3];
    out[(size_t)NROWS * DIM] = 1.25f * sse * (1.0f / (float)((size_t)NROWS * DIM));
    out[(size_t)NROWS * DIM + 1] = expf(e);
  }
}

extern "C" void kernel_launch(void* const* d_in, const int* in_sizes, int n_in,
                              void* d_out, int out_size, void* d_ws, size_t ws_size,
                              hipStream_t stream) {
  const float* d_inputs = (const float*)d_in[0];
  const float* d_cb = (const float*)d_in[1];
  float* out = (float*)d_out;
  char* ws = (char*)d_ws;

  u8* A = (u8*)(ws + OFF_A);
  u8* B = (u8*)(ws + OFF_B);
  float* norms = (float*)(ws + OFF_NORMS);
  float* rn = (float*)(ws + OFF_RN);
  u64* amin = (u64*)(ws + OFF_AMIN);
  u32* counts = (u32*)(ws + OFF_COUNTS);

  k_cvtA<<<NROWS, 256, 0, stream>>>((const float4*)d_inputs, (u32*)A, rn, amin);
  k_cvtB<<<NCODES, 256, 0, stream>>>(d_cb, (u32*)B, norms, counts);
  dim3 grid(NROWS / BM, NCODES / BN);
  k_gemm_argmin<<<grid, 512, 0, stream>>>(A, B, norms, amin);
  k_out<<<NROWS, 256, 0, stream>>>((const float4*)d_cb, amin, (float4*)out, counts);
  k_final<<<1, 256, 0, stream>>>(counts, amin, rn, out);
}

// Round 10
// 259.615 us; speedup vs baseline: 5.5795x; 1.0299x over previous
//
#include <hip/hip_runtime.h>
#include <hip/hip_bf16.h>
#include <stdint.h>

typedef unsigned int u32;
typedef unsigned char u8;
typedef unsigned long long u64;
typedef __attribute__((ext_vector_type(8))) int i32x8;
typedef __attribute__((ext_vector_type(4))) int i32x4;
typedef __attribute__((ext_vector_type(4))) float f32x4;

#define NROWS 8192    // 16*512
#define NCODES 4096
#define DIM 4096
#define BK 128
#define KSTEPS (DIM / BK)   // 32
#define BM 128
#define BN 128

// ---------------- workspace layout (bytes) ----------------
#define OFF_A      0UL
#define OFF_B      33554432UL
#define OFF_NORMS  50331648UL
#define OFF_RN     50348032UL
#define OFF_AMIN   50380800UL
#define OFF_COUNTS 50446336UL

__device__ __forceinline__ void stage16(const void* g, void* l) {
  __builtin_amdgcn_global_load_lds(
      (const __attribute__((address_space(1))) u32*)g,
      (__attribute__((address_space(3))) u32*)l, 16, 0, 0);
}

// float -> OCP e4m3fn, RNE, saturate to 448. Data is finite (no NaN path).
__device__ __forceinline__ u32 f2fp8(float f) {
  u32 u = __float_as_uint(f);
  u32 sign = (u >> 24) & 0x80u;
  u32 mag = u & 0x7FFFFFFFu;
  if (mag > 0x43E00000u) mag = 0x43E00000u;          // sat to 448
  u32 b;
  if (mag < 0x3C800000u) {                            // < 2^-6 : subnormal
    b = (u32)__float2int_rn(__uint_as_float(mag) * 512.0f);
  } else {
    u32 m = mag + 0x7FFFFu + ((mag >> 20) & 1u);      // RNE at 20-bit boundary
    u32 e = (m >> 23) - 127u;
    b = (((e + 7u) << 3) | ((m >> 20) & 7u)) & 0x7Fu;
  }
  return sign | b;
}

__device__ __forceinline__ u32 pack4(float4 v) {
  return f2fp8(v.x) | (f2fp8(v.y) << 8) | (f2fp8(v.z) << 16) | (f2fp8(v.w) << 24);
}

__device__ __forceinline__ float waveRed(float s) {
#pragma unroll
  for (int off = 32; off > 0; off >>= 1) s += __shfl_down(s, off);
  return s;
}

__device__ __forceinline__ i32x8 comb(i32x4 lo, i32x4 hi) {
  i32x8 r;
  r[0] = lo[0]; r[1] = lo[1]; r[2] = lo[2]; r[3] = lo[3];
  r[4] = hi[0]; r[5] = hi[1]; r[6] = hi[2]; r[7] = hi[3];
  return r;
}

// ---------------- inputs: fp32 -> fp8 + ||x||^2 per row (+ amin init) -------
__global__ void k_cvtA(const float4* __restrict__ in, u32* __restrict__ outA,
                       float* __restrict__ rn, u64* __restrict__ amin) {
  int r = blockIdx.x;
  if (threadIdx.x == 64) amin[r] = ~0ULL;   // fold k_init: one launch fewer
  const float4* src = in + (size_t)r * (DIM / 4);
  u32* dst = outA + (size_t)r * (DIM / 4);
  float s = 0.0f;
#pragma unroll
  for (int q = 0; q < 4; ++q) {
    int j = q * 256 + threadIdx.x;
    float4 v = src[j];
    s += v.x * v.x + v.y * v.y + v.z * v.z + v.w * v.w;
    dst[j] = pack4(v);
  }
  s = waveRed(s);
  __shared__ float red[4];
  int wid = threadIdx.x >> 6, lane = threadIdx.x & 63;
  if (lane == 0) red[wid] = s;
  __syncthreads();
  if (threadIdx.x == 0) rn[r] = red[0] + red[1] + red[2] + red[3];
}

// ---------------- codebook: fp32 -> fp8*4096 + ||e||^2 (+ counts init) ------
__global__ void k_cvtB(const float* __restrict__ cb, u32* __restrict__ Bb,
                       float* __restrict__ norms, u32* __restrict__ counts) {
  int row = blockIdx.x;
  if (threadIdx.x == 64) counts[row] = 0u;
  const float4* src = (const float4*)(cb + (size_t)row * DIM);
  u32* dst = Bb + (size_t)row * (DIM / 4);
  float s = 0.0f;
#pragma unroll
  for (int q = 0; q < 4; ++q) {
    int j = q * 256 + threadIdx.x;
    float4 v = src[j];
    s += v.x * v.x + v.y * v.y + v.z * v.z + v.w * v.w;
    float4 sv;
    sv.x = v.x * 4096.0f; sv.y = v.y * 4096.0f;
    sv.z = v.z * 4096.0f; sv.w = v.w * 4096.0f;
    dst[j] = pack4(sv);
  }
  s = waveRed(s);
  __shared__ float red[4];
  int wid = threadIdx.x >> 6, lane = threadIdx.x & 63;
  if (lane == 0) red[wid] = s;
  __syncthreads();
  if (threadIdx.x == 0) norms[row] = red[0] + red[1] + red[2] + red[3];
}

// ---------------- MX-fp8 GEMM (x . e^T) + per-row argmin ----------------
// 128x128 tile, BK=128 fp8, 4 waves (2x2), wave tile 64x64, acc[4][4] =
// 64 AGPRs. R9's 256^2/8-wave geometry was register-starved: acc alone
// took 128 of the 256 unified regs/wave -> persistent ~4-reg spill
// (125 MB scratch traffic) AND dirty vmcnt semantics (spill VMEM ops
// share the counter with stage loads). This geometry is R3's proven
// ~156-reg footprint (no spill) + static counted-vmcnt double-buffer
// (literal buffer ids) + 64 KB dbuf LDS -> 2-3 blocks/CU so cross-block
// wave overlap hides barrier/stage stalls.
// Chunk swizzle as before: pre-swizzled global source, linear LDS dest,
// swizzled conflict-free ds_read_b128.
__launch_bounds__(256)
__global__ void k_gemm_argmin(const u8* __restrict__ A,
                              const u8* __restrict__ B,
                              const float* __restrict__ norms,
                              u64* __restrict__ amin) {
  __shared__ u8 As[2][BM * BK];   // 2 x 16 KiB
  __shared__ u8 Bs[2][BN * BK];   // 2 x 16 KiB

  const int bm = blockIdx.x;
  const int bn = blockIdx.y;

  const int tid = threadIdx.x;
  const int w = tid >> 6;
  const int lane = tid & 63;
  const int wr = w >> 1, wc = w & 1;   // 2 x 2 wave grid
  const int g = lane >> 4, c = lane & 15;

  const size_t rowA0 = (size_t)bm * BM;
  const size_t rowB0 = (size_t)bn * BN;

  // stage-side swizzle: thread fills LDS chunk (tid&7) of row j*32+(tid>>3);
  // fetches global chunk (tid&7) ^ (row&7); row&7 == (tid>>3)&7 for all j.
  const int colb = (((tid & 7) ^ ((tid >> 3) & 7)) << 4);
  const int srow = tid >> 3;
  const u8* gA = A + rowA0 * DIM + colb;
  const u8* gB = B + rowB0 * DIM + colb;

  // read-side swizzle: fragment row&7 == c&7; halves at colo and colo^16.
  const int colo = (((2 * g) ^ (c & 7)) << 4);

  f32x4 acc[4][4] = {};

#define STAGE(buf, kt_)                                                   \
  {                                                                       \
    _Pragma("unroll") for (int j = 0; j < 4; ++j) {                       \
      int o = j * 4096 + tid * 16;                                        \
      int row = j * 32 + srow;                                            \
      stage16(gA + (size_t)row * DIM + (size_t)(kt_)*BK,                  \
              (char*)As[buf] + o);                                        \
      stage16(gB + (size_t)row * DIM + (size_t)(kt_)*BK,                  \
              (char*)Bs[buf] + o);                                        \
    }                                                                     \
  }

#define COMPUTE(buf)                                                      \
  {                                                                       \
    i32x8 bv[4];                                                          \
    _Pragma("unroll") for (int n = 0; n < 4; ++n) {                       \
      int rown = (wc * 64 + n * 16 + c) * BK;                             \
      bv[n] = comb(*(const i32x4*)&Bs[buf][rown + colo],                  \
                   *(const i32x4*)&Bs[buf][rown + (colo ^ 16)]);          \
    }                                                                     \
    _Pragma("unroll") for (int m = 0; m < 4; ++m) {                       \
      int rowm = (wr * 64 + m * 16 + c) * BK;                             \
      i32x8 af = comb(*(const i32x4*)&As[buf][rowm + colo],               \
                      *(const i32x4*)&As[buf][rowm + (colo ^ 16)]);       \
      _Pragma("unroll") for (int n = 0; n < 4; ++n)                       \
          acc[m][n] = __builtin_amdgcn_mfma_scale_f32_16x16x128_f8f6f4(   \
              af, bv[n], acc[m][n], 0, 0, 0, 0x7F7F7F7F, 0, 0x7F7F7F7F);  \
    }                                                                     \
  }

#define WAIT8_BAR()                                          \
  asm volatile("s_waitcnt vmcnt(8)" ::: "memory");           \
  __builtin_amdgcn_s_barrier();                              \
  __builtin_amdgcn_sched_barrier(0);

  // ---- prologue: stage tile 0 into buffer 0 (8 loads in flight) ----
  STAGE(0, 0);

#pragma unroll 1
  for (int kt2 = 0; kt2 < 15; ++kt2) {
    STAGE(1, 2 * kt2 + 1);        // outstanding: 16
    WAIT8_BAR();                  // tile 2*kt2 landed in buf0; prefetch in flight
    COMPUTE(0);                   // tile 2*kt2
    __builtin_amdgcn_s_barrier(); // all reads of buf0 done -> safe to restage
    STAGE(0, 2 * kt2 + 2);        // outstanding: 16
    WAIT8_BAR();                  // tile 2*kt2+1 landed in buf1
    COMPUTE(1);                   // tile 2*kt2+1
    __builtin_amdgcn_s_barrier(); // all reads of buf1 done
  }
  // ---- static epilogue: tiles 30 (buf0, already staged) and 31 ----
  STAGE(1, 31);                   // outstanding: 16
  WAIT8_BAR();                    // tile 30 landed
  COMPUTE(0);                     // tile 30
  asm volatile("s_waitcnt vmcnt(0)" ::: "memory");
  __builtin_amdgcn_s_barrier();   // every wave's tile-31 writes landed
  __builtin_amdgcn_sched_barrier(0);
  COMPUTE(1);                     // tile 31

#undef STAGE
#undef COMPUTE
#undef WAIT8_BAR

  // epilogue: d = ||e||^2 - (2/4096)*acc ; argmin over this block's 128 cols
  const int rowBase = bm * BM + wr * 64;
  const int colBase = bn * BN + wc * 64;
  float nr[4];
#pragma unroll
  for (int n = 0; n < 4; ++n) nr[n] = norms[colBase + n * 16 + c];

#pragma unroll
  for (int m = 0; m < 4; ++m) {
#pragma unroll
    for (int j = 0; j < 4; ++j) {
      u64 key = ~0ULL;
#pragma unroll
      for (int n = 0; n < 4; ++n) {
        float d = nr[n] - acc[m][n][j] * 4.8828125e-4f;   // 2/4096
        u32 u = __float_as_uint(d);
        u = (u & 0x80000000u) ? ~u : (u | 0x80000000u);
        u64 k2 = ((u64)u << 32) | (u32)(colBase + n * 16 + c);
        if (k2 < key) key = k2;
      }
#pragma unroll
      for (int off = 1; off < 16; off <<= 1) {
        u64 o = __shfl_xor(key, off);
        if (o < key) key = o;
      }
      if (c == 0) atomicMin(&amin[rowBase + m * 16 + g * 4 + j], key);
    }
  }
}

// ---------------- gather -> output + counts ----------------
__global__ void k_out(const float4* __restrict__ cb, const u64* __restrict__ amin,
                      float4* __restrict__ out, u32* __restrict__ counts) {
  int r = blockIdx.x;
  u32 idx = (u32)(amin[r] & 0xFFFFFFFFu);
  if (threadIdx.x == 0) atomicAdd(&counts[idx], 1u);
  const float4* crow = cb + (size_t)idx * (DIM / 4);
  float4* orow = out + (size_t)r * (DIM / 4);
#pragma unroll
  for (int q = 0; q < 4; ++q) {
    int j = q * 256 + threadIdx.x;
    orow[j] = crow[j];
  }
}

// ---------------- finalize: loss (from distances) + perplexity ----------------
__global__ void k_final(const u32* __restrict__ counts, const u64* __restrict__ amin,
                        const float* __restrict__ rn, float* __restrict__ out) {
  float acc = 0.0f;
  for (int r = threadIdx.x; r < NROWS; r += 256) {
    u32 u = (u32)(amin[r] >> 32);
    u32 b = (u & 0x80000000u) ? (u & 0x7FFFFFFFu) : ~u;  // undo sortable map
    acc += __uint_as_float(b) + rn[r];   // d_min + ||x||^2 = ||x - e||^2
  }
  float ent = 0.0f;
  for (int i = threadIdx.x; i < NCODES; i += 256) {
    float p = (float)counts[i] * (1.0f / (float)NROWS);
    ent -= p * logf(p + 1e-10f);
  }
  acc = waveRed(acc);
  ent = waveRed(ent);
  __shared__ float ra[4], re[4];
  int wid = threadIdx.x >> 6, lane = threadIdx.x & 63;
  if (lane == 0) { ra[wid] = acc; re[wid] = ent; }
  __syncthreads();
  if (threadIdx.x == 0) {
    float sse = ra[0] + ra[1] + ra[2] + ra[3];
    float e = re[0] + re[1] + re[2] + re[3];
    out[(size_t)NROWS * DIM] = 1.25f * sse * (1.0f / (float)((size_t)NROWS * DIM));
    out[(size_t)NROWS * DIM + 1] = expf(e);
  }
}

extern "C" void kernel_launch(void* const* d_in, const int* in_sizes, int n_in,
                              void* d_out, int out_size, void* d_ws, size_t ws_size,
                              hipStream_t stream) {
  const float* d_inputs = (const float*)d_in[0];
  const float* d_cb = (const float*)d_in[1];
  float* out = (float*)d_out;
  char* ws = (char*)d_ws;

  u8* A = (u8*)(ws + OFF_A);
  u8* B = (u8*)(ws + OFF_B);
  float* norms = (float*)(ws + OFF_NORMS);
  float* rn = (float*)(ws + OFF_RN);
  u64* amin = (u64*)(ws + OFF_AMIN);
  u32* counts = (u32*)(ws + OFF_COUNTS);

  k_cvtA<<<NROWS, 256, 0, stream>>>((const float4*)d_inputs, (u32*)A, rn, amin);
  k_cvtB<<<NCODES, 256, 0, stream>>>(d_cb, (u32*)B, norms, counts);
  dim3 grid(NROWS / BM, NCODES / BN);
  k_gemm_argmin<<<grid, 256, 0, stream>>>(A, B, norms, amin);
  k_out<<<NROWS, 256, 0, stream>>>((const float4*)d_cb, amin, (float4*)out, counts);
  k_final<<<1, 256, 0, stream>>>(counts, amin, rn, out);
}